// Round 7
// baseline (161.271 us; speedup 1.0000x reference)
//
#include <hip/hip_runtime.h>

#define NB   32
#define NCI  128
#define NH   64
#define NW   64
#define NCO  256
#define NOH  62
#define NOW  62

typedef __attribute__((ext_vector_type(8))) short bf16x8;           // 8 bf16 (4 VGPRs)
typedef __attribute__((ext_vector_type(8))) unsigned short u16x8;
typedef __attribute__((ext_vector_type(4))) float f32x4;

typedef __attribute__((address_space(1))) const unsigned int glb_u32_t;
typedef __attribute__((address_space(3))) unsigned int lds_u32_t;

// fp32 -> bf16 bits, round-to-nearest-even (finite inputs)
__device__ __forceinline__ unsigned short f2bf(float f) {
  unsigned int u = __float_as_uint(f);
  u = u + 0x7FFFu + ((u >> 16) & 1u);
  return (unsigned short)(u >> 16);
}

__device__ __forceinline__ void gload_lds16(const unsigned short* g, unsigned short* l) {
  __builtin_amdgcn_global_load_lds((glb_u32_t*)g, (lds_u32_t*)l, 16, 0, 0);
}

// x[b][ci][h][w] fp32 -> xt[b][h][w][ci] bf16, transposed through LDS.
__global__ __launch_bounds__(256) void cvt_x_kernel(const float* __restrict__ x,
                                                    unsigned short* __restrict__ xt) {
  __shared__ unsigned short l[64 * 130];   // 16640 B
  const int tid = threadIdx.x;
  const int b = blockIdx.x >> 6, h = blockIdx.x & 63;
  const int w0 = tid & 63, c0 = tid >> 6;
  const float* src = x + ((size_t)b * NCI * NH + h) * NW;
  #pragma unroll
  for (int g = 0; g < 32; ++g) {
    int ci = g * 4 + c0;
    l[w0 * 130 + ci] = f2bf(src[(size_t)ci * (NH * NW) + w0]);
  }
  __syncthreads();
  unsigned short* dst = xt + ((size_t)b * NH + h) * NW * NCI;
  #pragma unroll
  for (int it = 0; it < 4; ++it) {
    int gidx = it * 2048 + tid * 8;
    int w = gidx >> 7, ci0 = gidx & 127;
    const unsigned int* lw = (const unsigned int*)(l + w * 130 + ci0);
    union { u16x8 v; unsigned int u[4]; } t;
    t.u[0] = lw[0]; t.u[1] = lw[1]; t.u[2] = lw[2]; t.u[3] = lw[3];
    *(u16x8*)(dst + w * NCI + ci0) = t.v;
  }
}

// W[co][ci][kh][kw] fp32 -> wt[k][co][ci] bf16, coalesced 16B stores
__global__ __launch_bounds__(256) void cvt_w_kernel(const float* __restrict__ wsrc,
                                                    unsigned short* __restrict__ wt) {
  int t = blockIdx.x * 256 + threadIdx.x;            // 0 .. 9*256*16-1
  int oc = t & 15, co = (t >> 4) & 255, k = t >> 12;
  const float* src = wsrc + ((size_t)co * NCI + oc * 8) * 9 + k;
  u16x8 v;
  #pragma unroll
  for (int j = 0; j < 8; ++j) v[j] = f2bf(src[j * 9]);
  *(u16x8*)(wt + ((size_t)k * NCO + co) * NCI + oc * 8) = v;
}

// Implicit direct conv, bf16 MFMA 16x16x32.
// Wave tile 128 cout x 64 pix (8m x 4n) -> 0.375 ds_read_b128 per MFMA
// (was 0.5 with 4x4): the LDS-read/MFMA co-bound is the measured limiter.
// Block: 256 thr (4 waves, 2 wm x 2 wn), tile 256 cout x (2 oh x 64 ow);
// 31 ohg x 2 = 62 -> zero row padding. 36 steps s = cic*9 + tap; ws staged
// per tap (256x32 = 16 KB), xs per cic (16 KB), both dbuf: LDS 64 KB ->
// 2 blocks/CU (independent-block TLP). Counted-vmcnt skeleton (T4) + T5.
// Octet swizzle baked into gload_lds SOURCE (LDS dest linear); same XOR on
// read; measured 0 bank conflicts. xs w=64/65 overreads land in following
// smem regions (in-allocation; feed masked ow>=62 outputs only).
__global__ __launch_bounds__(256, 2) void conv_mfma_kernel(
    const unsigned short* __restrict__ xt, const unsigned short* __restrict__ wt,
    const float* __restrict__ bias, float* __restrict__ out) {
  __shared__ unsigned short smem[2 * (4 * 64 * 32) + 2 * (256 * 32)];  // 65536 B
  unsigned short* xsb[2] = { smem, smem + 8192 };
  unsigned short* wsb[2] = { smem + 16384, smem + 24576 };

  const int tid  = threadIdx.x;
  const int lane = tid & 63;
  const int wid  = tid >> 6;
  const int wm   = wid & 1;     // cout half (128)
  const int wn   = wid >> 1;    // output row within pair (0..1)
  const int l15  = lane & 15;
  const int lo   = lane >> 4;   // k-octet group

  // XCD-bijective swizzle: grid 992 = 8 * 124 exactly.
  const int bid0 = blockIdx.x;
  const int bid  = (bid0 & 7) * 124 + (bid0 >> 3);
  const int b    = bid / 31;
  const int ohg  = bid % 31;
  const int oh0  = ohg * 2;

  f32x4 acc[8][4];
  #pragma unroll
  for (int mi = 0; mi < 8; ++mi)
    #pragma unroll
    for (int ni = 0; ni < 4; ++ni)
      acc[mi][ni] = (f32x4){0.f, 0.f, 0.f, 0.f};

  const size_t xbase = (size_t)b * NH * NW * NCI;

  // stage xs for ci-chunk cic into buffer cic&1 (16 gload_lds, 4/wave)
  auto stage_x = [&](int cic) {
    unsigned short* dst = xsb[cic & 1];
    #pragma unroll
    for (int i = 0; i < 4; ++i) {
      int e = wid * 4 + i;                 // 0..15
      int u = e * 64 + lane;               // 0..1023
      int o = u & 3, w = (u >> 2) & 63, r = u >> 8;   // r 0..3 (oh0+3 <= 63)
      const unsigned short* src = xt + xbase
          + ((size_t)(oh0 + r) * NW + w) * NCI + cic * 32
          + (o ^ ((w >> 1) & 3)) * 8;
      gload_lds16(src, dst + e * 512);
    }
  };

  // stage ws for step s (one tap: 256 co x 32 ci = 16 KB; 16 gload_lds, 4/wave)
  auto stage_w = [&](int s) {
    int cic = s / 9, tap = s % 9;
    unsigned short* dst = wsb[s & 1];
    #pragma unroll
    for (int i = 0; i < 4; ++i) {
      int e = wid * 4 + i;                 // 0..15
      int v = e * 64 + lane;               // 0..1023
      int o = v & 3, co = v >> 2;          // co 0..255
      const unsigned short* src = wt
          + ((size_t)tap * NCO + co) * NCI + cic * 32
          + (o ^ ((co >> 1) & 3)) * 8;
      gload_lds16(src, dst + e * 512);
    }
  };

  // prologue: fill pipeline stage 0 (8 loads/thread), full drain once
  stage_w(0);
  stage_x(0);
  asm volatile("s_waitcnt vmcnt(0)" ::: "memory");
  __builtin_amdgcn_s_barrier();
  __builtin_amdgcn_sched_barrier(0);

  #pragma unroll
  for (int s = 0; s < 36; ++s) {
    const int cic = s / 9, tap = s % 9;
    const int kh = tap / 3, kw = tap % 3;

    // issue next step's staging (other parity; WAR-fenced by step s-1's end
    // barrier), then counted wait: just-issued loads STAY IN FLIGHT across
    // the barrier; older (step-s) loads are guaranteed retired.
    if (s < 35) {
      stage_w(s + 1);
      if ((s + 1) % 9 == 0) {
        stage_x((s + 1) / 9);
        asm volatile("s_waitcnt vmcnt(8)" ::: "memory");
      } else {
        asm volatile("s_waitcnt vmcnt(4)" ::: "memory");
      }
    } else {
      asm volatile("s_waitcnt vmcnt(0)" ::: "memory");
    }
    __builtin_amdgcn_s_barrier();          // all threads' step-s data in LDS
    __builtin_amdgcn_sched_barrier(0);

    // compute step s
    {
      unsigned short* xs = xsb[cic & 1];
      unsigned short* ws = wsb[s & 1];
      const int r = wn + kh;               // staged input row 0..3
      bf16x8 af[8], bfv[4];
      #pragma unroll
      for (int mi = 0; mi < 8; ++mi) {
        int co = wm * 128 + mi * 16 + l15;
        af[mi] = *(const bf16x8*)(ws +
            ((size_t)(co * 4 + (lo ^ ((co >> 1) & 3))) * 8));
      }
      #pragma unroll
      for (int ni = 0; ni < 4; ++ni) {
        int w = ni * 16 + l15 + kw;        // up to 65 -> in-allocation overread,
        bfv[ni] = *(const bf16x8*)(xs +    // masked outputs only
            ((size_t)((r * 64 + w) * 4 + (lo ^ ((w >> 1) & 3))) * 8));
      }
      __builtin_amdgcn_s_setprio(1);       // T5: favor MFMA-issuing wave
      #pragma unroll
      for (int mi = 0; mi < 8; ++mi)
        #pragma unroll
        for (int ni = 0; ni < 4; ++ni)
          acc[mi][ni] = __builtin_amdgcn_mfma_f32_16x16x32_bf16(
              af[mi], bfv[ni], acc[mi][ni], 0, 0, 0);
      __builtin_amdgcn_s_setprio(0);
    }

    // WAR fence: all waves consumed this parity before next iter restages it
    if (s < 35) {
      __builtin_amdgcn_s_barrier();
      __builtin_amdgcn_sched_barrier(0);
    }
  }

  // epilogue: D row = (lane>>4)*4 + reg (cout), col = lane&15 (ow)
  const int oh = oh0 + wn;                 // <= 61, no row mask needed
  #pragma unroll
  for (int mi = 0; mi < 8; ++mi) {
    int co0 = wm * 128 + mi * 16 + lo * 4;
    const f32x4 bv = *(const f32x4*)(bias + co0);
    #pragma unroll
    for (int ni = 0; ni < 4; ++ni) {
      int ow = ni * 16 + l15;
      if (ow < NOW) {
        size_t o0 = (((size_t)b * NCO + co0) * NOH + oh) * NOW + ow;
        const size_t cs = (size_t)NOH * NOW;
        out[o0]          = acc[mi][ni][0] + bv[0];
        out[o0 + cs]     = acc[mi][ni][1] + bv[1];
        out[o0 + 2 * cs] = acc[mi][ni][2] + bv[2];
        out[o0 + 3 * cs] = acc[mi][ni][3] + bv[3];
      }
    }
  }
}

// Safety-net: correct fp32 direct conv (used only if ws_size too small)
__global__ __launch_bounds__(256) void conv_naive_kernel(
    const float* __restrict__ x, const float* __restrict__ w,
    const float* __restrict__ bias, float* __restrict__ out) {
  long t = (long)blockIdx.x * 256 + threadIdx.x;
  const long total = (long)NB * NCO * NOH * NOW;
  if (t >= total) return;
  int ow = (int)(t % NOW);
  int oh = (int)((t / NOW) % NOH);
  int co = (int)((t / ((long)NOW * NOH)) % NCO);
  int b  = (int)(t / ((long)NOW * NOH * NCO));
  float acc = bias[co];
  for (int ci = 0; ci < NCI; ++ci) {
    const float* xp = x + (((size_t)b * NCI + ci) * NH + oh) * NW + ow;
    const float* wp = w + ((size_t)co * NCI + ci) * 9;
    #pragma unroll
    for (int kh = 0; kh < 3; ++kh)
      #pragma unroll
      for (int kw = 0; kw < 3; ++kw)
        acc += xp[kh * NW + kw] * wp[kh * 3 + kw];
  }
  out[t] = acc;
}

extern "C" void kernel_launch(void* const* d_in, const int* in_sizes, int n_in,
                              void* d_out, int out_size, void* d_ws, size_t ws_size,
                              hipStream_t stream) {
  const float* x    = (const float*)d_in[0];
  const float* w    = (const float*)d_in[1];
  const float* bias = (const float*)d_in[2];
  float* out        = (float*)d_out;

  const size_t WT_BYTES = (size_t)9 * NCO * NCI * 2;             // 589824
  const size_t XT_BYTES = (size_t)NB * NH * NW * NCI * 2;        // 33554432

  if (ws_size >= WT_BYTES + XT_BYTES) {
    unsigned short* wt = (unsigned short*)d_ws;
    unsigned short* xt = (unsigned short*)((char*)d_ws + WT_BYTES);
    cvt_w_kernel<<<(9 * NCO * 16) / 256, 256, 0, stream>>>(w, wt);
    cvt_x_kernel<<<NB * NH, 256, 0, stream>>>(x, xt);
    conv_mfma_kernel<<<31 * NB, 256, 0, stream>>>(xt, wt, bias, out);
  } else {
    const long total = (long)NB * NCO * NOH * NOW;
    conv_naive_kernel<<<(int)((total + 255) / 256), 256, 0, stream>>>(x, w, bias, out);
  }
}

// Round 8
// 97.954 us; speedup vs baseline: 1.6464x; 1.6464x over previous
//
#include <hip/hip_runtime.h>

#define NB   32
#define NCI  128
#define NH   64
#define NW   64
#define NCO  256
#define NOH  62
#define NOW  62

typedef __attribute__((ext_vector_type(8))) short bf16x8;           // 8 bf16 (4 VGPRs)
typedef __attribute__((ext_vector_type(8))) unsigned short u16x8;
typedef __attribute__((ext_vector_type(4))) float f32x4;

typedef __attribute__((address_space(1))) const unsigned int glb_u32_t;
typedef __attribute__((address_space(3))) unsigned int lds_u32_t;

// fp32 -> bf16 bits, round-to-nearest-even (finite inputs)
__device__ __forceinline__ unsigned short f2bf(float f) {
  unsigned int u = __float_as_uint(f);
  u = u + 0x7FFFu + ((u >> 16) & 1u);
  return (unsigned short)(u >> 16);
}

__device__ __forceinline__ void gload_lds16(const unsigned short* g, unsigned short* l) {
  __builtin_amdgcn_global_load_lds((glb_u32_t*)g, (lds_u32_t*)l, 16, 0, 0);
}

// x[b][ci][h][w] fp32 -> xt[b][h][w][ci] bf16, transposed through LDS.
__global__ __launch_bounds__(256) void cvt_x_kernel(const float* __restrict__ x,
                                                    unsigned short* __restrict__ xt) {
  __shared__ unsigned short l[64 * 130];   // 16640 B
  const int tid = threadIdx.x;
  const int b = blockIdx.x >> 6, h = blockIdx.x & 63;
  const int w0 = tid & 63, c0 = tid >> 6;
  const float* src = x + ((size_t)b * NCI * NH + h) * NW;
  #pragma unroll
  for (int g = 0; g < 32; ++g) {
    int ci = g * 4 + c0;
    l[w0 * 130 + ci] = f2bf(src[(size_t)ci * (NH * NW) + w0]);
  }
  __syncthreads();
  unsigned short* dst = xt + ((size_t)b * NH + h) * NW * NCI;
  #pragma unroll
  for (int it = 0; it < 4; ++it) {
    int gidx = it * 2048 + tid * 8;
    int w = gidx >> 7, ci0 = gidx & 127;
    const unsigned int* lw = (const unsigned int*)(l + w * 130 + ci0);
    union { u16x8 v; unsigned int u[4]; } t;
    t.u[0] = lw[0]; t.u[1] = lw[1]; t.u[2] = lw[2]; t.u[3] = lw[3];
    *(u16x8*)(dst + w * NCI + ci0) = t.v;
  }
}

// W[co][ci][kh][kw] fp32 -> wt[k][co][ci] bf16, coalesced 16B stores
__global__ __launch_bounds__(256) void cvt_w_kernel(const float* __restrict__ wsrc,
                                                    unsigned short* __restrict__ wt) {
  int t = blockIdx.x * 256 + threadIdx.x;            // 0 .. 9*256*16-1
  int oc = t & 15, co = (t >> 4) & 255, k = t >> 12;
  const float* src = wsrc + ((size_t)co * NCI + oc * 8) * 9 + k;
  u16x8 v;
  #pragma unroll
  for (int j = 0; j < 8; ++j) v[j] = f2bf(src[j * 9]);
  *(u16x8*)(wt + ((size_t)k * NCO + co) * NCI + oc * 8) = v;
}

// Implicit direct conv, bf16 MFMA 16x16x32.
// Wave tile 128 cout x 64 pix (8m x 4n): 12 ds_read_b128 per 32 MFMA (0.375).
// Block: 256 thr (4 waves, 2 wm x 2 wn), tile 256 cout x (2 oh x 64 ow).
// 36 steps s = cic*9 + tap. LDS 80 KB -> 2 blocks/CU:
//   xs: 2 bufs x [4r][64w][32ci] (16 KB, parity cic&1), shorts [0,16384)
//   ws: 3 bufs x [256co][32ci]   (16 KB, index tap%3),   shorts [16384,40960)
// ONE barrier per tap; stage(s+2) issued between ds_read and MFMA (depth-2
// prefetch); counted vmcnt 4/8, vmcnt(0) only at the last step. WAR safe:
// a wave passing barrier_s has consumed step-(s-1) reads (MFMA issue =>
// operands in regs); stage(s+2) writes buf (s-1)%3, read last at step s-1.
// All LDS-read addresses = 4 per-lane VGPR bases + static offsets (swizzle
// XOR is mi/ni-invariant: (co>>1)&3=(l15>>1)&3, (w>>1)&3=((l15+kw)>>1)&3).
// Anti-spill: outer cic loop NOT unrolled. Target: acc 128 AGPR + <=128 VGPR.
__global__ __launch_bounds__(256, 2) void conv_mfma_kernel(
    const unsigned short* __restrict__ xt, const unsigned short* __restrict__ wt,
    const float* __restrict__ bias, float* __restrict__ out) {
  __shared__ unsigned short smem[2 * 8192 + 3 * 8192];   // 81920 B

  const int tid  = threadIdx.x;
  const int lane = tid & 63;
  const int wid  = tid >> 6;
  const int wm   = wid & 1;     // cout half (128)
  const int wn   = wid >> 1;    // output row within pair (0..1)
  const int l15  = lane & 15;
  const int lo   = lane >> 4;   // k-octet group

  // XCD-bijective swizzle: grid 992 = 8 * 124 exactly.
  const int bid0 = blockIdx.x;
  const int bid  = (bid0 & 7) * 124 + (bid0 >> 3);
  const int b    = bid / 31;
  const int ohg  = bid % 31;
  const int oh0  = ohg * 2;

  f32x4 acc[8][4];
  #pragma unroll
  for (int mi = 0; mi < 8; ++mi)
    #pragma unroll
    for (int ni = 0; ni < 4; ++ni)
      acc[mi][ni] = (f32x4){0.f, 0.f, 0.f, 0.f};

  // ---- per-lane LDS read bases (bytes); everything else is a static offset
  const char* sm = (const char*)smem;
  const int af_lane = (wm * 128 + l15) * 64 + ((lo ^ ((l15 >> 1) & 3)) * 16);
  int bf_lane[3];
  #pragma unroll
  for (int kw = 0; kw < 3; ++kw)
    bf_lane[kw] = wn * 4096 + (l15 + kw) * 64
                + ((lo ^ (((l15 + kw) >> 1) & 3)) * 16);

  // ---- persistent staging source pointers (per-lane constant parts)
  const size_t xbase = (size_t)b * NH * NW * NCI;
  const unsigned short* xsrc[4];
  const unsigned short* wsrcp[4];
  #pragma unroll
  for (int i = 0; i < 4; ++i) {
    int u = (wid * 4 + i) * 64 + lane;
    int o = u & 3, w = (u >> 2) & 63, r = u >> 8;          // r 0..3
    xsrc[i] = xt + xbase + ((size_t)(oh0 + r) * NW + w) * NCI
            + ((o ^ ((w >> 1) & 3)) * 8);
    int v = (wid * 4 + i) * 64 + lane;
    int o2 = v & 3, co = v >> 2;                            // co 0..255
    wsrcp[i] = wt + (size_t)co * NCI + ((o2 ^ ((co >> 1) & 3)) * 8);
  }
  const int ebase = wid * 4;   // LDS dest chunk index base

  // stage ws tap t for ci-chunk c into ws buf t%3 (4 gload_lds / wave)
  auto stage_w = [&](int c, int t) {
    unsigned short* dst = smem + 16384 + (t % 3) * 8192;
    const size_t so = (size_t)t * NCO * NCI + c * 32;
    #pragma unroll
    for (int i = 0; i < 4; ++i)
      gload_lds16(wsrcp[i] + so, dst + (ebase + i) * 512);
  };
  // stage xs chunk c into xs buf c&1 (4 gload_lds / wave)
  auto stage_x = [&](int c) {
    unsigned short* dst = smem + (c & 1) * 8192;
    #pragma unroll
    for (int i = 0; i < 4; ++i)
      gload_lds16(xsrc[i] + c * 32, dst + (ebase + i) * 512);
  };

  // prologue: stage(0) [w0 + x0] then stage(1) [w1]
  stage_w(0, 0);
  stage_x(0);
  stage_w(0, 1);

  for (int cic = 0; cic < 4; ++cic) {          // NOT unrolled (anti-spill)
    const int xoff = (cic & 1) * 16384;        // xs buffer byte base
    #pragma unroll
    for (int tap = 0; tap < 9; ++tap) {        // ws buf = tap%3 (static)
      const int kh = tap / 3, kw = tap % 3;

      // counted wait: youngest outstanding = stage(s+1); retire stage(s).
      if (tap == 8) {
        if (cic == 3) { asm volatile("s_waitcnt vmcnt(0)" ::: "memory"); }
        else          { asm volatile("s_waitcnt vmcnt(8)" ::: "memory"); }
      } else {
        asm volatile("s_waitcnt vmcnt(4)" ::: "memory");
      }
      __builtin_amdgcn_s_barrier();
      __builtin_amdgcn_sched_barrier(0);

      // ds reads: 8 af (1 base + imm) + 4 bfv (3 bases + imm)
      bf16x8 af[8], bfv[4];
      #pragma unroll
      for (int mi = 0; mi < 8; ++mi)
        af[mi] = *(const bf16x8*)(sm + 32768 + (tap % 3) * 16384
                                  + mi * 1024 + af_lane);
      #pragma unroll
      for (int ni = 0; ni < 4; ++ni)            // w up to 65: overread stays
        bfv[ni] = *(const bf16x8*)(sm + xoff + kh * 4096 + ni * 1024
                                   + bf_lane[kw]);   // in-allocation, masked

      // issue stage(s+2) now -> flies under the MFMA cluster (depth 2)
      if (tap <= 6) {
        stage_w(cic, tap + 2);
      } else if (tap == 7) {
        if (cic < 3) { stage_w(cic + 1, 0); stage_x(cic + 1); }
      } else {
        if (cic < 3) stage_w(cic + 1, 1);
      }

      __builtin_amdgcn_s_setprio(1);            // T5
      #pragma unroll
      for (int mi = 0; mi < 8; ++mi)
        #pragma unroll
        for (int ni = 0; ni < 4; ++ni)
          acc[mi][ni] = __builtin_amdgcn_mfma_f32_16x16x32_bf16(
              af[mi], bfv[ni], acc[mi][ni], 0, 0, 0);
      __builtin_amdgcn_s_setprio(0);
    }
  }

  // epilogue: D row = lo*4 + reg (cout), col = l15 (ow)
  const int oh = oh0 + wn;                     // <= 61
  #pragma unroll
  for (int mi = 0; mi < 8; ++mi) {
    int co0 = wm * 128 + mi * 16 + lo * 4;
    const f32x4 bv = *(const f32x4*)(bias + co0);
    #pragma unroll
    for (int ni = 0; ni < 4; ++ni) {
      int ow = ni * 16 + l15;
      if (ow < NOW) {
        size_t o0 = (((size_t)b * NCO + co0) * NOH + oh) * NOW + ow;
        const size_t cs = (size_t)NOH * NOW;
        out[o0]          = acc[mi][ni][0] + bv[0];
        out[o0 + cs]     = acc[mi][ni][1] + bv[1];
        out[o0 + 2 * cs] = acc[mi][ni][2] + bv[2];
        out[o0 + 3 * cs] = acc[mi][ni][3] + bv[3];
      }
    }
  }
}

// Safety-net: correct fp32 direct conv (used only if ws_size too small)
__global__ __launch_bounds__(256) void conv_naive_kernel(
    const float* __restrict__ x, const float* __restrict__ w,
    const float* __restrict__ bias, float* __restrict__ out) {
  long t = (long)blockIdx.x * 256 + threadIdx.x;
  const long total = (long)NB * NCO * NOH * NOW;
  if (t >= total) return;
  int ow = (int)(t % NOW);
  int oh = (int)((t / NOW) % NOH);
  int co = (int)((t / ((long)NOW * NOH)) % NCO);
  int b  = (int)(t / ((long)NOW * NOH * NCO));
  float acc = bias[co];
  for (int ci = 0; ci < NCI; ++ci) {
    const float* xp = x + (((size_t)b * NCI + ci) * NH + oh) * NW + ow;
    const float* wp = w + ((size_t)co * NCI + ci) * 9;
    #pragma unroll
    for (int kh = 0; kh < 3; ++kh)
      #pragma unroll
      for (int kw = 0; kw < 3; ++kw)
        acc += xp[kh * NW + kw] * wp[kh * 3 + kw];
  }
  out[t] = acc;
}

extern "C" void kernel_launch(void* const* d_in, const int* in_sizes, int n_in,
                              void* d_out, int out_size, void* d_ws, size_t ws_size,
                              hipStream_t stream) {
  const float* x    = (const float*)d_in[0];
  const float* w    = (const float*)d_in[1];
  const float* bias = (const float*)d_in[2];
  float* out        = (float*)d_out;

  const size_t WT_BYTES = (size_t)9 * NCO * NCI * 2;             // 589824
  const size_t XT_BYTES = (size_t)NB * NH * NW * NCI * 2;        // 33554432

  if (ws_size >= WT_BYTES + XT_BYTES) {
    unsigned short* wt = (unsigned short*)d_ws;
    unsigned short* xt = (unsigned short*)((char*)d_ws + WT_BYTES);
    cvt_w_kernel<<<(9 * NCO * 16) / 256, 256, 0, stream>>>(w, wt);
    cvt_x_kernel<<<NB * NH, 256, 0, stream>>>(x, xt);
    conv_mfma_kernel<<<31 * NB, 256, 0, stream>>>(xt, wt, bias, out);
  } else {
    const long total = (long)NB * NCO * NOH * NOW;
    conv_naive_kernel<<<(int)((total + 255) / 256), 256, 0, stream>>>(x, w, bias, out);
  }
}